// Round 1
// baseline (130.123 us; speedup 1.0000x reference)
//
#include <hip/hip_runtime.h>
#include <math.h>

#define N_ 32
#define C_ 512
#define CR_ 64
#define HW_ 3136
#define HW4_ 784
constexpr float EPS = 1e-5f;

// ---------------- Kernel 1: global average pool ----------------
// One block per (n,c) row; 3136 contiguous floats = 784 float4.
__global__ __launch_bounds__(256) void pool_kernel(const float* __restrict__ x,
                                                   float* __restrict__ pooled) {
    const int row = blockIdx.x;  // n*C + c
    const float4* xr = reinterpret_cast<const float4*>(x + (size_t)row * HW_);
    float acc = 0.f;
    for (int j = threadIdx.x; j < HW4_; j += 256) {
        float4 v = xr[j];
        acc += (v.x + v.y) + (v.z + v.w);
    }
    // wave (64-lane) reduce
    for (int o = 32; o; o >>= 1) acc += __shfl_down(acc, o, 64);
    __shared__ float s[4];
    if ((threadIdx.x & 63) == 0) s[threadIdx.x >> 6] = acc;
    __syncthreads();
    if (threadIdx.x == 0) {
        pooled[row] = (s[0] + s[1] + s[2] + s[3]) * (1.0f / HW_);
    }
}

// ---------------- Kernel 2: the tiny MLP + GN + gate ----------------
// One block per sample. 512 threads.
__global__ __launch_bounds__(512) void gate_kernel(
    const float* __restrict__ pooled,
    const float* __restrict__ w1, const float* __restrict__ b1,
    const float* __restrict__ gn1_w, const float* __restrict__ gn1_b,
    const float* __restrict__ w2, const float* __restrict__ b2,
    const float* __restrict__ gn2_w, const float* __restrict__ gn2_b,
    float* __restrict__ gate)
{
    const int n = blockIdx.x;
    const int tid = threadIdx.x;
    __shared__ float sp[C_];
    __shared__ float sh[CR_];
    __shared__ float sred[8];

    sp[tid] = pooled[n * C_ + tid];
    __syncthreads();

    // h[r] = sum_c pooled[c] * w1[r*C+c] + b1[r] ; 8 threads per output r
    {
        const int r = tid >> 3;
        const int l8 = tid & 7;
        float acc = 0.f;
        for (int c = l8; c < C_; c += 8) acc += sp[c] * w1[r * C_ + c];
        acc += __shfl_xor(acc, 1, 64);
        acc += __shfl_xor(acc, 2, 64);
        acc += __shfl_xor(acc, 4, 64);
        if (l8 == 0) sh[r] = acc + b1[r];
    }
    __syncthreads();

    // GroupNorm(1) over 64 values + ELU, done by the first wave
    if (tid < 64) {
        float v = sh[tid];
        float s = v;
        for (int o = 32; o; o >>= 1) s += __shfl_xor(s, o, 64);
        const float mu = s * (1.0f / CR_);
        const float d = v - mu;
        float vv = d * d;
        for (int o = 32; o; o >>= 1) vv += __shfl_xor(vv, o, 64);
        const float var = vv * (1.0f / CR_);
        float xn = d * rsqrtf(var + EPS);
        xn = xn * gn1_w[tid] + gn1_b[tid];
        sh[tid] = xn > 0.f ? xn : expm1f(xn);  // ELU alpha=1
    }
    __syncthreads();

    // g[c] = sum_r h[r] * w2[c*CR+r] + b2[c]  (thread per channel c)
    float g = b2[tid];
    #pragma unroll 8
    for (int r = 0; r < CR_; ++r) g += sh[r] * w2[tid * CR_ + r];

    // GroupNorm(1) over 512 values (block reduce: 8 waves)
    float s = g;
    for (int o = 32; o; o >>= 1) s += __shfl_xor(s, o, 64);
    if ((tid & 63) == 0) sred[tid >> 6] = s;
    __syncthreads();
    const float mu = (sred[0] + sred[1] + sred[2] + sred[3] +
                      sred[4] + sred[5] + sred[6] + sred[7]) * (1.0f / C_);
    const float d = g - mu;
    float vv = d * d;
    for (int o = 32; o; o >>= 1) vv += __shfl_xor(vv, o, 64);
    __syncthreads();  // sred reuse
    if ((tid & 63) == 0) sred[tid >> 6] = vv;
    __syncthreads();
    const float var = (sred[0] + sred[1] + sred[2] + sred[3] +
                       sred[4] + sred[5] + sred[6] + sred[7]) * (1.0f / C_);
    float xn = d * rsqrtf(var + EPS) * gn2_w[tid] + gn2_b[tid];
    gate[n * C_ + tid] = 1.0f / (1.0f + expf(-xn));
}

// ---------------- Kernel 3: broadcast scale ----------------
__global__ __launch_bounds__(256) void scale_kernel(const float* __restrict__ x,
                                                    const float* __restrict__ gate,
                                                    float* __restrict__ out) {
    const float4* x4 = reinterpret_cast<const float4*>(x);
    float4* o4 = reinterpret_cast<float4*>(out);
    const int total4 = N_ * C_ * HW4_;  // 12,845,056
    for (int i = blockIdx.x * blockDim.x + threadIdx.x; i < total4;
         i += gridDim.x * blockDim.x) {
        const float g = gate[i / HW4_];  // 784 float4 per channel, no straddle
        float4 v = x4[i];
        v.x *= g; v.y *= g; v.z *= g; v.w *= g;
        o4[i] = v;
    }
}

extern "C" void kernel_launch(void* const* d_in, const int* in_sizes, int n_in,
                              void* d_out, int out_size, void* d_ws, size_t ws_size,
                              hipStream_t stream) {
    const float* x     = (const float*)d_in[0];
    const float* w1    = (const float*)d_in[1];
    const float* b1    = (const float*)d_in[2];
    const float* gn1_w = (const float*)d_in[3];
    const float* gn1_b = (const float*)d_in[4];
    const float* w2    = (const float*)d_in[5];
    const float* b2    = (const float*)d_in[6];
    const float* gn2_w = (const float*)d_in[7];
    const float* gn2_b = (const float*)d_in[8];
    float* out = (float*)d_out;

    float* pooled = (float*)d_ws;          // 32*512 floats
    float* gate   = pooled + N_ * C_;      // 32*512 floats

    pool_kernel<<<N_ * C_, 256, 0, stream>>>(x, pooled);
    gate_kernel<<<N_, 512, 0, stream>>>(pooled, w1, b1, gn1_w, gn1_b,
                                        w2, b2, gn2_w, gn2_b, gate);
    scale_kernel<<<2048, 256, 0, stream>>>(x, gate, out);
}

// Round 3
// 110.929 us; speedup vs baseline: 1.1730x; 1.1730x over previous
//
#include <hip/hip_runtime.h>
#include <math.h>

#define N_ 32
#define C_ 512
#define CR_ 64
#define HW_ 3136
#define HW4_ 784
constexpr float EPS = 1e-5f;

typedef float f4 __attribute__((ext_vector_type(4)));  // native vec for nontemporal builtins

// ---------------- Kernel 1: global average pool ----------------
// One block per (n,c) row; 3136 contiguous floats = 784 float4.
__global__ __launch_bounds__(256) void pool_kernel(const float* __restrict__ x,
                                                   float* __restrict__ pooled) {
    const int row = blockIdx.x;  // n*C + c
    const f4* xr = reinterpret_cast<const f4*>(x + (size_t)row * HW_);
    float acc = 0.f;
    for (int j = threadIdx.x; j < HW4_; j += 256) {
        f4 v = xr[j];
        acc += (v.x + v.y) + (v.z + v.w);
    }
    // wave (64-lane) reduce
    for (int o = 32; o; o >>= 1) acc += __shfl_down(acc, o, 64);
    __shared__ float s[4];
    if ((threadIdx.x & 63) == 0) s[threadIdx.x >> 6] = acc;
    __syncthreads();
    if (threadIdx.x == 0) {
        pooled[row] = (s[0] + s[1] + s[2] + s[3]) * (1.0f / HW_);
    }
}

// ---------------- Kernel 2: the tiny MLP + GN + gate ----------------
// One block per sample. 512 threads.
__global__ __launch_bounds__(512) void gate_kernel(
    const float* __restrict__ pooled,
    const float* __restrict__ w1, const float* __restrict__ b1,
    const float* __restrict__ gn1_w, const float* __restrict__ gn1_b,
    const float* __restrict__ w2, const float* __restrict__ b2,
    const float* __restrict__ gn2_w, const float* __restrict__ gn2_b,
    float* __restrict__ gate)
{
    const int n = blockIdx.x;
    const int tid = threadIdx.x;
    __shared__ float sp[C_];
    __shared__ float sh[CR_];
    __shared__ float sred[8];

    sp[tid] = pooled[n * C_ + tid];
    __syncthreads();

    // h[r] = sum_c pooled[c] * w1[r*C+c] + b1[r] ; 8 threads per output r
    {
        const int r = tid >> 3;
        const int l8 = tid & 7;
        float acc = 0.f;
        for (int c = l8; c < C_; c += 8) acc += sp[c] * w1[r * C_ + c];
        acc += __shfl_xor(acc, 1, 64);
        acc += __shfl_xor(acc, 2, 64);
        acc += __shfl_xor(acc, 4, 64);
        if (l8 == 0) sh[r] = acc + b1[r];
    }
    __syncthreads();

    // GroupNorm(1) over 64 values + ELU, done by the first wave
    if (tid < 64) {
        float v = sh[tid];
        float s = v;
        for (int o = 32; o; o >>= 1) s += __shfl_xor(s, o, 64);
        const float mu = s * (1.0f / CR_);
        const float d = v - mu;
        float vv = d * d;
        for (int o = 32; o; o >>= 1) vv += __shfl_xor(vv, o, 64);
        const float var = vv * (1.0f / CR_);
        float xn = d * rsqrtf(var + EPS);
        xn = xn * gn1_w[tid] + gn1_b[tid];
        sh[tid] = xn > 0.f ? xn : expm1f(xn);  // ELU alpha=1
    }
    __syncthreads();

    // g[c] = sum_r h[r] * w2[c*CR+r] + b2[c]  (thread per channel c)
    float g = b2[tid];
    #pragma unroll 8
    for (int r = 0; r < CR_; ++r) g += sh[r] * w2[tid * CR_ + r];

    // GroupNorm(1) over 512 values (block reduce: 8 waves)
    float s = g;
    for (int o = 32; o; o >>= 1) s += __shfl_xor(s, o, 64);
    if ((tid & 63) == 0) sred[tid >> 6] = s;
    __syncthreads();
    const float mu = (sred[0] + sred[1] + sred[2] + sred[3] +
                      sred[4] + sred[5] + sred[6] + sred[7]) * (1.0f / C_);
    const float d = g - mu;
    float vv = d * d;
    for (int o = 32; o; o >>= 1) vv += __shfl_xor(vv, o, 64);
    __syncthreads();  // sred reuse
    if ((tid & 63) == 0) sred[tid >> 6] = vv;
    __syncthreads();
    const float var = (sred[0] + sred[1] + sred[2] + sred[3] +
                       sred[4] + sred[5] + sred[6] + sred[7]) * (1.0f / C_);
    float xn = d * rsqrtf(var + EPS) * gn2_w[tid] + gn2_b[tid];
    gate[n * C_ + tid] = 1.0f / (1.0f + expf(-xn));
}

// ---------------- Kernel 3: broadcast scale ----------------
// One block per (n,c) row: gate is a single scalar broadcast, no division,
// contiguous float4 sweep. Non-temporal stores keep x resident in L3.
__global__ __launch_bounds__(256) void scale_kernel(const float* __restrict__ x,
                                                    const float* __restrict__ gate,
                                                    float* __restrict__ out) {
    const int row = blockIdx.x;  // n*C + c
    const float g = gate[row];
    const f4* xr = reinterpret_cast<const f4*>(x + (size_t)row * HW_);
    f4* orow = reinterpret_cast<f4*>(out + (size_t)row * HW_);
    for (int j = threadIdx.x; j < HW4_; j += 256) {
        f4 v = xr[j];
        v.x *= g; v.y *= g; v.z *= g; v.w *= g;
        __builtin_nontemporal_store(v, &orow[j]);
    }
}

extern "C" void kernel_launch(void* const* d_in, const int* in_sizes, int n_in,
                              void* d_out, int out_size, void* d_ws, size_t ws_size,
                              hipStream_t stream) {
    const float* x     = (const float*)d_in[0];
    const float* w1    = (const float*)d_in[1];
    const float* b1    = (const float*)d_in[2];
    const float* gn1_w = (const float*)d_in[3];
    const float* gn1_b = (const float*)d_in[4];
    const float* w2    = (const float*)d_in[5];
    const float* b2    = (const float*)d_in[6];
    const float* gn2_w = (const float*)d_in[7];
    const float* gn2_b = (const float*)d_in[8];
    float* out = (float*)d_out;

    float* pooled = (float*)d_ws;          // 32*512 floats
    float* gate   = pooled + N_ * C_;      // 32*512 floats

    pool_kernel<<<N_ * C_, 256, 0, stream>>>(x, pooled);
    gate_kernel<<<N_, 512, 0, stream>>>(pooled, w1, b1, gn1_w, gn1_b,
                                        w2, b2, gn2_w, gn2_b, gate);
    scale_kernel<<<N_ * C_, 256, 0, stream>>>(x, gate, out);
}